// Round 1
// baseline (74.314 us; speedup 1.0000x reference)
//
#include <hip/hip_runtime.h>
#include <cmath>

#define BB 256
#define TT 2048
#define ATTN_RNN 1024
#define HIDDEN 128
#define STATIC_CH 8
#define STATIC_K 21
#define DYN_CH 8
#define DYN_K 21
#define PRIOR_LEN 11

struct PriorArg { float v[PRIOR_LEN]; };

__device__ __forceinline__ float fast_tanh(float x) {
    float e = __expf(2.0f * x);
    return 1.0f - 2.0f * __builtin_amdgcn_rcpf(e + 1.0f);
}

__global__ __launch_bounds__(1024, 1) void dca_kernel(
    const float* __restrict__ s,  const float* __restrict__ alpha,
    const float* __restrict__ Ww, const float* __restrict__ Wb,
    const float* __restrict__ Vw, const float* __restrict__ Fw,
    const float* __restrict__ Uw, const float* __restrict__ Tw,
    const float* __restrict__ Tb, const float* __restrict__ vw,
    float* __restrict__ out, PriorArg pf)
{
    const int b   = blockIdx.x;
    const int tid = threadIdx.x;

    __shared__ float s_sh[ATTN_RNN];
    __shared__ float part_sh[8][HIDDEN];
    __shared__ float h_sh[HIDDEN];
    __shared__ float G_sh[DYN_CH * DYN_K];
    __shared__ float Weff_sh[HIDDEN * 24];     // rows padded 21 -> 24 (f4-aligned)
    __shared__ float a_sh[TT + 24];            // a_sh[i] = alpha[b, i-10] (0-padded)
    __shared__ float Tb_sh[HIDDEN], v_sh[HIDDEN];
    __shared__ float red_max[16], red_sum[16];

    // ---- stage inputs ----
    for (int i = tid; i < ATTN_RNN; i += 1024) s_sh[i] = s[b * ATTN_RNN + i];
    for (int i = tid; i < TT + 24; i += 1024)
        a_sh[i] = (i >= 10 && i < TT + 10) ? alpha[b * TT + (i - 10)] : 0.0f;
    if (tid < HIDDEN) { Tb_sh[tid] = Tb[tid]; v_sh[tid] = vw[tid]; }
    __syncthreads();

    // ---- phase 1: h = tanh(s @ Ww^T + Wb), 8-way split-K ----
    {
        int j = tid & (HIDDEN - 1);
        int part = tid >> 7;                       // 0..7, 128 i's each
        const float4* w4 = (const float4*)(Ww + j * ATTN_RNN + part * 128);
        const float4* s4 = (const float4*)(s_sh + part * 128);
        float acc = 0.f;
        #pragma unroll
        for (int i = 0; i < 32; ++i) {
            float4 w = w4[i]; float4 sv = s4[i];
            acc = fmaf(w.x, sv.x, acc); acc = fmaf(w.y, sv.y, acc);
            acc = fmaf(w.z, sv.z, acc); acc = fmaf(w.w, sv.w, acc);
        }
        part_sh[part][j] = acc;
    }
    __syncthreads();
    if (tid < HIDDEN) {
        float a = Wb[tid];
        #pragma unroll
        for (int p = 0; p < 8; ++p) a += part_sh[p][tid];
        h_sh[tid] = fast_tanh(a);
    }
    __syncthreads();

    // ---- phase 2: G = h @ Vw^T (168 outputs) ----
    if (tid < DYN_CH * DYN_K) {
        const float* vr = Vw + tid * HIDDEN;
        float acc = 0.f;
        #pragma unroll 4
        for (int j = 0; j < HIDDEN; ++j) acc = fmaf(vr[j], h_sh[j], acc);
        G_sh[tid] = acc;
    }
    __syncthreads();

    // ---- phase 3: Weff[j][k] = sum_c U[j,c]*F[c,k] + T[j,c]*G[c,k] ----
    for (int idx = tid; idx < HIDDEN * 24; idx += 1024) {
        int j = idx / 24, k = idx % 24;
        float acc = 0.f;
        if (k < 21) {
            #pragma unroll
            for (int c = 0; c < 8; ++c) {
                acc = fmaf(Uw[j * 8 + c], Fw[c * 21 + k], acc);
                acc = fmaf(Tw[j * 8 + c], G_sh[c * 21 + k], acc);
            }
        }
        Weff_sh[idx] = acc;
    }
    __syncthreads();

    // ---- phase 4: two positions per thread ----
    const int t0 = tid * 2;
    float aw[22];
    #pragma unroll
    for (int i = 0; i < 22; ++i) aw[i] = a_sh[t0 + i];   // aw[k] = alpha[t0+k-10]

    float acc0 = 0.f, acc1 = 0.f;
    for (int j = 0; j < HIDDEN; ++j) {
        const float4* w4 = (const float4*)(&Weff_sh[j * 24]);
        float p0 = Tb_sh[j], p1 = p0;
        #pragma unroll
        for (int kk = 0; kk < 5; ++kk) {
            float4 w = w4[kk];
            p0 = fmaf(w.x, aw[4 * kk + 0], p0);
            p1 = fmaf(w.x, aw[4 * kk + 1], p1);
            p0 = fmaf(w.y, aw[4 * kk + 1], p0);
            p1 = fmaf(w.y, aw[4 * kk + 2], p1);
            p0 = fmaf(w.z, aw[4 * kk + 2], p0);
            p1 = fmaf(w.z, aw[4 * kk + 3], p1);
            p0 = fmaf(w.w, aw[4 * kk + 3], p0);
            p1 = fmaf(w.w, aw[4 * kk + 4], p1);
        }
        float wl = Weff_sh[j * 24 + 20];
        p0 = fmaf(wl, aw[20], p0);
        p1 = fmaf(wl, aw[21], p1);
        float vj = v_sh[j];
        acc0 = fmaf(vj, fast_tanh(p0), acc0);
        acc1 = fmaf(vj, fast_tanh(p1), acc1);
    }

    // prior: p[t] = sum_k alpha[t+k-10] * pf[k]
    float pr0 = 0.f, pr1 = 0.f;
    #pragma unroll
    for (int k = 0; k < PRIOR_LEN; ++k) {
        pr0 = fmaf(aw[k],     pf.v[k], pr0);
        pr1 = fmaf(aw[k + 1], pf.v[k], pr1);
    }
    float e0 = acc0 + __logf(fmaxf(pr0, 1e-6f));
    float e1 = acc1 + __logf(fmaxf(pr1, 1e-6f));

    // ---- softmax over T within block ----
    const int wid = tid >> 6, lane = tid & 63;
    float m = fmaxf(e0, e1);
    #pragma unroll
    for (int o = 32; o > 0; o >>= 1) m = fmaxf(m, __shfl_xor(m, o));
    if (lane == 0) red_max[wid] = m;
    __syncthreads();
    float gm = red_max[0];
    #pragma unroll
    for (int w = 1; w < 16; ++w) gm = fmaxf(gm, red_max[w]);

    float x0 = __expf(e0 - gm), x1 = __expf(e1 - gm);
    float sloc = x0 + x1;
    #pragma unroll
    for (int o = 32; o > 0; o >>= 1) sloc += __shfl_xor(sloc, o);
    if (lane == 0) red_sum[wid] = sloc;
    __syncthreads();
    float gs = 0.f;
    #pragma unroll
    for (int w = 0; w < 16; ++w) gs += red_sum[w];
    float inv = 1.0f / gs;

    ((float2*)(out + b * TT))[tid] = make_float2(x0 * inv, x1 * inv);
}

extern "C" void kernel_launch(void* const* d_in, const int* in_sizes, int n_in,
                              void* d_out, int out_size, void* d_ws, size_t ws_size,
                              hipStream_t stream) {
    (void)in_sizes; (void)n_in; (void)d_ws; (void)ws_size; (void)out_size;

    // beta-binomial prior filter, flipped (host-side pure math; graph-safe)
    PriorArg pf;
    const double a = 0.1, bpr = 0.9;
    const int n = PRIOR_LEN - 1;
    const double norm = lgamma(a) + lgamma(bpr) - lgamma(a + bpr);
    for (int k = 0; k <= n; ++k) {
        double lp = lgamma((double)n + 1.0) - lgamma((double)k + 1.0)
                  - lgamma((double)(n - k) + 1.0)
                  + lgamma((double)k + a) + lgamma((double)(n - k) + bpr)
                  - lgamma((double)n + a + bpr) - norm;
        pf.v[PRIOR_LEN - 1 - k] = (float)exp(lp);
    }

    dca_kernel<<<dim3(BB), dim3(1024), 0, stream>>>(
        (const float*)d_in[0], (const float*)d_in[1], (const float*)d_in[2],
        (const float*)d_in[3], (const float*)d_in[4], (const float*)d_in[5],
        (const float*)d_in[6], (const float*)d_in[7], (const float*)d_in[8],
        (const float*)d_in[9], (float*)d_out, pf);
}

// Round 2
// 72.286 us; speedup vs baseline: 1.0281x; 1.0281x over previous
//
#include <hip/hip_runtime.h>
#include <cmath>

#define BB 256
#define TT 2048
#define ATTN_RNN 1024
#define HIDDEN 128
#define DYN_CH 8
#define DYN_K 21
#define PRIOR_LEN 11
#define KSCALE 2.8853900817779268f   /* 2*log2(e) */

struct PriorArg { float v[PRIOR_LEN]; };

__device__ __forceinline__ float fast_tanh(float x) {
    float e = __expf(2.0f * x);
    return 1.0f - 2.0f * __builtin_amdgcn_rcpf(e + 1.0f);
}

// Weff_sh row layout (stride 24 floats):
//   [0..20]  = KSCALE * (U@F + T@G)[j][k]      (conv taps, pre-scaled)
//   [21]     = KSCALE * Tb[j]
//   [22]     = v[j]
//   [23]     = pad
__global__ __launch_bounds__(1024, 1) void dca_kernel(
    const float* __restrict__ s,  const float* __restrict__ alpha,
    const float* __restrict__ Ww, const float* __restrict__ Wb,
    const float* __restrict__ Vw, const float* __restrict__ Fw,
    const float* __restrict__ Uw, const float* __restrict__ Tw,
    const float* __restrict__ Tb, const float* __restrict__ vw,
    float* __restrict__ out, PriorArg pf)
{
    const int b   = blockIdx.x;
    const int tid = threadIdx.x;

    __shared__ float s_sh[ATTN_RNN];
    __shared__ float part_sh[8][HIDDEN];
    __shared__ float h_sh[HIDDEN];
    __shared__ float G_sh[DYN_CH * DYN_K];
    __shared__ float Weff_sh[HIDDEN * 24];
    __shared__ float a_sh[TT + 24];            // a_sh[i] = alpha[b, i-10] (0-padded)
    __shared__ float red_max[16], red_sum[16];
    __shared__ float sumv_sh;

    // ---- stage inputs ----
    for (int i = tid; i < ATTN_RNN; i += 1024) s_sh[i] = s[b * ATTN_RNN + i];
    for (int i = tid; i < TT + 24; i += 1024)
        a_sh[i] = (i >= 10 && i < TT + 10) ? alpha[b * TT + (i - 10)] : 0.0f;
    __syncthreads();

    // ---- phase 1: h = tanh(s @ Ww^T + Wb), 8-way split-K ----
    {
        int j = tid & (HIDDEN - 1);
        int part = tid >> 7;                       // 0..7, 128 i's each
        const float4* w4 = (const float4*)(Ww + j * ATTN_RNN + part * 128);
        const float4* s4 = (const float4*)(s_sh + part * 128);
        float acc = 0.f;
        #pragma unroll
        for (int i = 0; i < 32; ++i) {
            float4 w = w4[i]; float4 sv = s4[i];
            acc = fmaf(w.x, sv.x, acc); acc = fmaf(w.y, sv.y, acc);
            acc = fmaf(w.z, sv.z, acc); acc = fmaf(w.w, sv.w, acc);
        }
        part_sh[part][j] = acc;
    }
    __syncthreads();
    if (tid < HIDDEN) {
        float a = Wb[tid];
        #pragma unroll
        for (int p = 0; p < 8; ++p) a += part_sh[p][tid];
        h_sh[tid] = fast_tanh(a);
    }
    __syncthreads();

    // ---- phase 2: G = h @ Vw^T (168 outputs) ----
    if (tid < DYN_CH * DYN_K) {
        const float4* vr = (const float4*)(Vw + tid * HIDDEN);
        const float4* hh = (const float4*)h_sh;
        float acc = 0.f;
        #pragma unroll
        for (int j = 0; j < 32; ++j) {
            float4 v4 = vr[j]; float4 h4 = hh[j];
            acc = fmaf(v4.x, h4.x, acc); acc = fmaf(v4.y, h4.y, acc);
            acc = fmaf(v4.z, h4.z, acc); acc = fmaf(v4.w, h4.w, acc);
        }
        G_sh[tid] = acc;
    }
    __syncthreads();

    // ---- phase 3: build pre-scaled Weff rows (+Tb, +v packed) ----
    for (int idx = tid; idx < HIDDEN * 24; idx += 1024) {
        int j = idx / 24, k = idx - j * 24;
        float val = 0.f;
        if (k < 21) {
            float acc = 0.f;
            #pragma unroll
            for (int c = 0; c < 8; ++c) {
                acc = fmaf(Uw[j * 8 + c], Fw[c * 21 + k], acc);
                acc = fmaf(Tw[j * 8 + c], G_sh[c * 21 + k], acc);
            }
            val = KSCALE * acc;
        } else if (k == 21) {
            val = KSCALE * Tb[j];
        } else if (k == 22) {
            val = vw[j];
        }
        Weff_sh[idx] = val;
    }
    if (tid < 64) {                                  // sum_v
        float sv = vw[tid] + vw[tid + 64];
        #pragma unroll
        for (int o = 32; o > 0; o >>= 1) sv += __shfl_xor(sv, o);
        if (tid == 0) sumv_sh = sv;
    }
    __syncthreads();

    // ---- phase 4: two positions per thread, pipelined j-loop ----
    const int t0 = tid * 2;
    float aw[22];
    #pragma unroll
    for (int i = 0; i < 22; ++i) aw[i] = a_sh[t0 + i];   // aw[k] = alpha[t0+k-10]

    float acc0 = 0.f, acc1 = 0.f;

#define LDW(J, W0, W1, W2, W3, W4, WQ) {                         \
        const float4* w4_ = (const float4*)(&Weff_sh[(J) * 24]); \
        W0 = w4_[0]; W1 = w4_[1]; W2 = w4_[2];                   \
        W3 = w4_[3]; W4 = w4_[4]; WQ = w4_[5]; }

#define TAP4(W, KB)                                                      \
        p0 = fmaf(W.x, aw[(KB)+0], p0); p1 = fmaf(W.x, aw[(KB)+1], p1); \
        p0 = fmaf(W.y, aw[(KB)+1], p0); p1 = fmaf(W.y, aw[(KB)+2], p1); \
        p0 = fmaf(W.z, aw[(KB)+2], p0); p1 = fmaf(W.z, aw[(KB)+3], p1); \
        p0 = fmaf(W.w, aw[(KB)+3], p0); p1 = fmaf(W.w, aw[(KB)+4], p1);

#define STEP(W0, W1, W2, W3, W4, WQ) {                           \
        float p0 = fmaf(WQ.x, aw[20], WQ.y);                     \
        float p1 = fmaf(WQ.x, aw[21], WQ.y);                     \
        TAP4(W0, 0) TAP4(W1, 4) TAP4(W2, 8)                      \
        TAP4(W3, 12) TAP4(W4, 16)                                \
        float r0 = __builtin_amdgcn_rcpf(__builtin_amdgcn_exp2f(p0) + 1.0f); \
        float r1 = __builtin_amdgcn_rcpf(__builtin_amdgcn_exp2f(p1) + 1.0f); \
        acc0 = fmaf(WQ.z, r0, acc0);                             \
        acc1 = fmaf(WQ.z, r1, acc1); }

    {
        float4 A0, A1, A2, A3, A4, AQ;
        float4 B0, B1, B2, B3, B4, BQ;
        LDW(0, A0, A1, A2, A3, A4, AQ);
        for (int j = 0; j < HIDDEN - 2; j += 2) {
            LDW(j + 1, B0, B1, B2, B3, B4, BQ);
            STEP(A0, A1, A2, A3, A4, AQ);
            LDW(j + 2, A0, A1, A2, A3, A4, AQ);
            STEP(B0, B1, B2, B3, B4, BQ);
        }
        LDW(HIDDEN - 1, B0, B1, B2, B3, B4, BQ);
        STEP(A0, A1, A2, A3, A4, AQ);
        STEP(B0, B1, B2, B3, B4, BQ);
    }

    // prior: p[t] = sum_k alpha[t+k-10] * pf[k]
    float pr0 = 0.f, pr1 = 0.f;
    #pragma unroll
    for (int k = 0; k < PRIOR_LEN; ++k) {
        pr0 = fmaf(aw[k],     pf.v[k], pr0);
        pr1 = fmaf(aw[k + 1], pf.v[k], pr1);
    }
    const float sumv = sumv_sh;
    float e0 = sumv - 2.0f * acc0 + __logf(fmaxf(pr0, 1e-6f));
    float e1 = sumv - 2.0f * acc1 + __logf(fmaxf(pr1, 1e-6f));

    // ---- softmax over T within block ----
    const int wid = tid >> 6, lane = tid & 63;
    float m = fmaxf(e0, e1);
    #pragma unroll
    for (int o = 32; o > 0; o >>= 1) m = fmaxf(m, __shfl_xor(m, o));
    if (lane == 0) red_max[wid] = m;
    __syncthreads();
    float gm = red_max[0];
    #pragma unroll
    for (int w = 1; w < 16; ++w) gm = fmaxf(gm, red_max[w]);

    float x0 = __expf(e0 - gm), x1 = __expf(e1 - gm);
    float sloc = x0 + x1;
    #pragma unroll
    for (int o = 32; o > 0; o >>= 1) sloc += __shfl_xor(sloc, o);
    if (lane == 0) red_sum[wid] = sloc;
    __syncthreads();
    float gs = 0.f;
    #pragma unroll
    for (int w = 0; w < 16; ++w) gs += red_sum[w];
    float inv = 1.0f / gs;

    ((float2*)(out + b * TT))[tid] = make_float2(x0 * inv, x1 * inv);
}

extern "C" void kernel_launch(void* const* d_in, const int* in_sizes, int n_in,
                              void* d_out, int out_size, void* d_ws, size_t ws_size,
                              hipStream_t stream) {
    (void)in_sizes; (void)n_in; (void)d_ws; (void)ws_size; (void)out_size;

    // beta-binomial prior filter, flipped (host-side pure math; graph-safe)
    PriorArg pf;
    const double a = 0.1, bpr = 0.9;
    const int n = PRIOR_LEN - 1;
    const double norm = lgamma(a) + lgamma(bpr) - lgamma(a + bpr);
    for (int k = 0; k <= n; ++k) {
        double lp = lgamma((double)n + 1.0) - lgamma((double)k + 1.0)
                  - lgamma((double)(n - k) + 1.0)
                  + lgamma((double)k + a) + lgamma((double)(n - k) + bpr)
                  - lgamma((double)n + a + bpr) - norm;
        pf.v[PRIOR_LEN - 1 - k] = (float)exp(lp);
    }

    dca_kernel<<<dim3(BB), dim3(1024), 0, stream>>>(
        (const float*)d_in[0], (const float*)d_in[1], (const float*)d_in[2],
        (const float*)d_in[3], (const float*)d_in[4], (const float*)d_in[5],
        (const float*)d_in[6], (const float*)d_in[7], (const float*)d_in[8],
        (const float*)d_in[9], (float*)d_out, pf);
}

// Round 3
// 45.053 us; speedup vs baseline: 1.6495x; 1.6045x over previous
//
#include <hip/hip_runtime.h>
#include <cmath>

#define BB 256
#define TT 2048
#define ATTN_RNN 1024
#define HIDDEN 128
#define DYN_CH 8
#define DYN_K 21
#define PRIOR_LEN 11
#define KSCALE 2.8853900817779268f   /* 2*log2(e) */

typedef __attribute__((ext_vector_type(8))) short  short8v;   // 8 bf16
typedef __attribute__((ext_vector_type(4))) float  float4v;

struct PriorArg { float v[PRIOR_LEN]; };

__device__ __forceinline__ short f2bf(float f) {   // RNE float->bf16
    unsigned u = __float_as_uint(f);
    u += 0x7fffu + ((u >> 16) & 1u);
    return (short)(u >> 16);
}

__device__ __forceinline__ float fast_tanh(float x) {
    float e = __expf(2.0f * x);
    return 1.0f - 2.0f * __builtin_amdgcn_rcpf(e + 1.0f);
}

__global__ __launch_bounds__(1024, 1) void dca_kernel(
    const float* __restrict__ s,  const float* __restrict__ alpha,
    const float* __restrict__ Ww, const float* __restrict__ Wb,
    const float* __restrict__ Vw, const float* __restrict__ Fw,
    const float* __restrict__ Uw, const float* __restrict__ Tw,
    const float* __restrict__ Tb, const float* __restrict__ vw,
    float* __restrict__ out, PriorArg pf)
{
    const int b    = blockIdx.x;
    const int tid  = threadIdx.x;
    const int lane = tid & 63;
    const int wid  = tid >> 6;          // 0..15
    const int row  = lane & 15;
    const int kb   = lane >> 4;         // 0..3 (k-block of 8)

    __shared__ __align__(16) float s_sh[ATTN_RNN];
    __shared__ float part_sh[8][HIDDEN];
    __shared__ __align__(16) float h_sh[HIDDEN];
    __shared__ float G_sh[DYN_CH * DYN_K];
    __shared__ __align__(16) float Weff_sh[HIDDEN * 24];  // [j][k], k 21..23 = 0, KSCALE folded
    __shared__ float tb_sh[HIDDEN];                       // KSCALE * Tb
    __shared__ float vv_sh[HIDDEN];                       // v
    __shared__ __align__(16) float a_sh[TT + 48];         // a_sh[i] = alpha[b, i-10], 0-padded
    __shared__ __align__(16) float e_sh[TT];              // sum_j v_j * sigma  per position
    __shared__ float red_max[16], red_sum[16];
    __shared__ float sumv_sh;

    // ---- stage inputs ----
    for (int i = tid; i < ATTN_RNN; i += 1024) s_sh[i] = s[b * ATTN_RNN + i];
    for (int i = tid; i < TT + 48; i += 1024)
        a_sh[i] = (i >= 10 && i < TT + 10) ? alpha[b * TT + (i - 10)] : 0.0f;
    __syncthreads();

    // ---- phase 1: h = tanh(s @ Ww^T + Wb), 8-way split-K ----
    {
        int j = tid & (HIDDEN - 1);
        int part = tid >> 7;
        const float4* w4 = (const float4*)(Ww + j * ATTN_RNN + part * 128);
        const float4* s4 = (const float4*)(s_sh + part * 128);
        float acc = 0.f;
        #pragma unroll
        for (int i = 0; i < 32; ++i) {
            float4 w = w4[i]; float4 sv = s4[i];
            acc = fmaf(w.x, sv.x, acc); acc = fmaf(w.y, sv.y, acc);
            acc = fmaf(w.z, sv.z, acc); acc = fmaf(w.w, sv.w, acc);
        }
        part_sh[part][j] = acc;
    }
    __syncthreads();
    if (tid < HIDDEN) {
        float a = Wb[tid];
        #pragma unroll
        for (int p = 0; p < 8; ++p) a += part_sh[p][tid];
        h_sh[tid] = fast_tanh(a);
    }
    __syncthreads();

    // ---- phase 2: G = h @ Vw^T (168 outputs) ----
    if (tid < DYN_CH * DYN_K) {
        const float4* vr = (const float4*)(Vw + tid * HIDDEN);
        const float4* hh = (const float4*)h_sh;
        float acc = 0.f;
        #pragma unroll
        for (int j = 0; j < 32; ++j) {
            float4 v4 = vr[j]; float4 h4 = hh[j];
            acc = fmaf(v4.x, h4.x, acc); acc = fmaf(v4.y, h4.y, acc);
            acc = fmaf(v4.z, h4.z, acc); acc = fmaf(v4.w, h4.w, acc);
        }
        G_sh[tid] = acc;
    }
    __syncthreads();

    // ---- phase 3: Weff[j][k] = KSCALE*(U@F + T@G), k>=21 zeroed ----
    for (int idx = tid; idx < HIDDEN * 24; idx += 1024) {
        int j = idx / 24, k = idx - j * 24;
        float val = 0.f;
        if (k < 21) {
            float acc = 0.f;
            #pragma unroll
            for (int c = 0; c < 8; ++c) {
                acc = fmaf(Uw[j * 8 + c], Fw[c * 21 + k], acc);
                acc = fmaf(Tw[j * 8 + c], G_sh[c * 21 + k], acc);
            }
            val = KSCALE * acc;
        }
        Weff_sh[idx] = val;
    }
    if (tid < HIDDEN) { tb_sh[tid] = KSCALE * Tb[tid]; vv_sh[tid] = vw[tid]; }
    if (tid < 64) {
        float sv = vw[tid] + vw[tid + 64];
        #pragma unroll
        for (int o = 32; o > 0; o >>= 1) sv += __shfl_xor(sv, o);
        if (tid == 0) sumv_sh = sv;
    }
    __syncthreads();

    // ---- phase 4: MFMA Toeplitz conv. B-frags (Weff^T) once per wave ----
    // B[k][j]: lane holds k = kb*8+e, j = ntile*16+row. k>=24 block (kb==3) is zero.
    short8v bfrag[8];
    float tbr[8], vvr[8];
    #pragma unroll
    for (int n = 0; n < 8; ++n) {
        int j = n * 16 + row;
        short8v t;
        #pragma unroll
        for (int e = 0; e < 8; ++e) t[e] = 0;
        if (kb < 3) {
            const float* wb = &Weff_sh[j * 24 + kb * 8];
            #pragma unroll
            for (int e = 0; e < 8; ++e) t[e] = f2bf(wb[e]);
        }
        bfrag[n] = t;
        tbr[n] = tb_sh[j];
        vvr[n] = vv_sh[j];
    }

    // Each wave: 8 t-tiles of 16 positions.
    for (int i = 0; i < 8; ++i) {
        const int t0 = (wid * 8 + i) * 16;
        // A[r][k] = alpha[t0+r+k-10] = a_sh[t0+r+k]; lane: r=row, k=kb*8+e
        const float* ab = &a_sh[t0 + row + kb * 8];
        short8v af;
        #pragma unroll
        for (int e = 0; e < 8; ++e) af[e] = f2bf(ab[e]);

        float4v accs[8];
        #pragma unroll
        for (int n = 0; n < 8; ++n) {
            float4v z = {0.f, 0.f, 0.f, 0.f};
            accs[n] = __builtin_amdgcn_mfma_f32_16x16x32_bf16(af, bfrag[n], z, 0, 0, 0);
        }
        // epilogue: pv[r] += v_j * sigmoid-like(acc + tb)
        float4v pv = {0.f, 0.f, 0.f, 0.f};
        #pragma unroll
        for (int n = 0; n < 8; ++n) {
            #pragma unroll
            for (int r = 0; r < 4; ++r) {
                float p = accs[n][r] + tbr[n];
                float sg = __builtin_amdgcn_rcpf(__builtin_amdgcn_exp2f(p) + 1.0f);
                pv[r] = fmaf(vvr[n], sg, pv[r]);
            }
        }
        // reduce over the 16 j-lanes (low 4 lane bits)
        #pragma unroll
        for (int o = 1; o < 16; o <<= 1) {
            #pragma unroll
            for (int r = 0; r < 4; ++r) pv[r] += __shfl_xor(pv[r], o);
        }
        // C/D rows: row = kb*4 + r  -> positions t0 + kb*4 + r
        if ((lane & 15) == 0)
            *reinterpret_cast<float4v*>(&e_sh[t0 + kb * 4]) = pv;
    }
    __syncthreads();

    // ---- final: prior + softmax, 2 positions per thread ----
    const float sumv = sumv_sh;
    const int tp = tid * 2;
    float tot0 = e_sh[tp], tot1 = e_sh[tp + 1];
    float pr0 = 0.f, pr1 = 0.f;
    #pragma unroll
    for (int k = 0; k < PRIOR_LEN; ++k) {
        pr0 = fmaf(a_sh[tp + k],     pf.v[k], pr0);
        pr1 = fmaf(a_sh[tp + 1 + k], pf.v[k], pr1);
    }
    float e0 = sumv - 2.f * tot0 + __logf(fmaxf(pr0, 1e-6f));
    float e1 = sumv - 2.f * tot1 + __logf(fmaxf(pr1, 1e-6f));

    const int lwid = tid >> 6, llane = tid & 63;
    float m = fmaxf(e0, e1);
    #pragma unroll
    for (int o = 32; o > 0; o >>= 1) m = fmaxf(m, __shfl_xor(m, o));
    if (llane == 0) red_max[lwid] = m;
    __syncthreads();
    float gm = red_max[0];
    #pragma unroll
    for (int w = 1; w < 16; ++w) gm = fmaxf(gm, red_max[w]);

    float x0 = __expf(e0 - gm), x1 = __expf(e1 - gm);
    float sloc = x0 + x1;
    #pragma unroll
    for (int o = 32; o > 0; o >>= 1) sloc += __shfl_xor(sloc, o);
    if (llane == 0) red_sum[lwid] = sloc;
    __syncthreads();
    float gs = 0.f;
    #pragma unroll
    for (int w = 0; w < 16; ++w) gs += red_sum[w];
    float inv = 1.0f / gs;

    ((float2*)(out + b * TT))[tid] = make_float2(x0 * inv, x1 * inv);
}

extern "C" void kernel_launch(void* const* d_in, const int* in_sizes, int n_in,
                              void* d_out, int out_size, void* d_ws, size_t ws_size,
                              hipStream_t stream) {
    (void)in_sizes; (void)n_in; (void)d_ws; (void)ws_size; (void)out_size;

    PriorArg pf;
    const double a = 0.1, bpr = 0.9;
    const int n = PRIOR_LEN - 1;
    const double norm = lgamma(a) + lgamma(bpr) - lgamma(a + bpr);
    for (int k = 0; k <= n; ++k) {
        double lp = lgamma((double)n + 1.0) - lgamma((double)k + 1.0)
                  - lgamma((double)(n - k) + 1.0)
                  + lgamma((double)k + a) + lgamma((double)(n - k) + bpr)
                  - lgamma((double)n + a + bpr) - norm;
        pf.v[PRIOR_LEN - 1 - k] = (float)exp(lp);
    }

    dca_kernel<<<dim3(BB), dim3(1024), 0, stream>>>(
        (const float*)d_in[0], (const float*)d_in[1], (const float*)d_in[2],
        (const float*)d_in[3], (const float*)d_in[4], (const float*)d_in[5],
        (const float*)d_in[6], (const float*)d_in[7], (const float*)d_in[8],
        (const float*)d_in[9], (float*)d_out, pf);
}

// Round 4
// 44.395 us; speedup vs baseline: 1.6739x; 1.0148x over previous
//
#include <hip/hip_runtime.h>
#include <hip/hip_bf16.h>
#include <cmath>

#define BB 256
#define TT 2048
#define ATTN_RNN 1024
#define HIDDEN 128
#define DYN_CH 8
#define DYN_K 21
#define PRIOR_LEN 11
#define KSCALE 2.8853900817779268f   /* 2*log2(e) */

typedef __attribute__((ext_vector_type(8))) short  short8v;   // 8 bf16
typedef __attribute__((ext_vector_type(4))) float  float4v;

struct PriorArg { float v[PRIOR_LEN]; };

__device__ __forceinline__ float fast_tanh(float x) {
    float e = __expf(2.0f * x);
    return 1.0f - 2.0f * __builtin_amdgcn_rcpf(e + 1.0f);
}

__device__ __forceinline__ void setpk(short8v& d, int i, float lo, float hi) {
    union { __hip_bfloat162 h; short s[2]; } u;
    u.h = __float22bfloat162_rn(make_float2(lo, hi));   // v_cvt_pk_bf16_f32
    d[i] = u.s[0]; d[i + 1] = u.s[1];
}

__global__ __launch_bounds__(1024, 4) void dca_kernel(
    const float* __restrict__ s,  const float* __restrict__ alpha,
    const float* __restrict__ Ww, const float* __restrict__ Wb,
    const float* __restrict__ Vw, const float* __restrict__ Fw,
    const float* __restrict__ Uw, const float* __restrict__ Tw,
    const float* __restrict__ Tb, const float* __restrict__ vw,
    float* __restrict__ out, PriorArg pf)
{
    const int b    = blockIdx.x;
    const int tid  = threadIdx.x;
    const int lane = tid & 63;
    const int wid  = tid >> 6;          // 0..15
    const int row  = lane & 15;         // A: j-row within tile / B: t-col within tile
    const int kb   = lane >> 4;         // 0..3 (k-block of 8)

    __shared__ __align__(16) float s_sh[ATTN_RNN];
    __shared__ float part_sh[8][HIDDEN];
    __shared__ __align__(16) float h_sh[HIDDEN];
    __shared__ float G_sh[DYN_CH * DYN_K];
    // Weff_sh[j][k] (stride 24): k0..20 = KSCALE*(U@F+T@G); k21 = KSCALE*Tb[j]; k22,23 = 0
    __shared__ __align__(16) float Weff_sh[HIDDEN * 24];
    __shared__ float vv_sh[HIDDEN];
    __shared__ __align__(16) float a_sh[TT + 48];         // a_sh[i] = alpha[b, i-10], 0-padded
    __shared__ __align__(16) float e_sh[TT];              // sum_j v_j * sigma  per position
    __shared__ float red_max[16], red_sum[16];
    __shared__ float sumv_sh;

    // ---- stage inputs ----
    for (int i = tid; i < ATTN_RNN; i += 1024) s_sh[i] = s[b * ATTN_RNN + i];
    for (int i = tid; i < TT + 48; i += 1024)
        a_sh[i] = (i >= 10 && i < TT + 10) ? alpha[b * TT + (i - 10)] : 0.0f;
    __syncthreads();

    // ---- phase 1: h = tanh(s @ Ww^T + Wb), 8-way split-K ----
    {
        int j = tid & (HIDDEN - 1);
        int part = tid >> 7;
        const float4* w4 = (const float4*)(Ww + j * ATTN_RNN + part * 128);
        const float4* s4 = (const float4*)(s_sh + part * 128);
        float acc = 0.f;
        #pragma unroll
        for (int i = 0; i < 32; ++i) {
            float4 w = w4[i]; float4 sv = s4[i];
            acc = fmaf(w.x, sv.x, acc); acc = fmaf(w.y, sv.y, acc);
            acc = fmaf(w.z, sv.z, acc); acc = fmaf(w.w, sv.w, acc);
        }
        part_sh[part][j] = acc;
    }
    __syncthreads();
    if (tid < HIDDEN) {
        float a = Wb[tid];
        #pragma unroll
        for (int p = 0; p < 8; ++p) a += part_sh[p][tid];
        h_sh[tid] = fast_tanh(a);
    }
    __syncthreads();

    // ---- phase 2: G = h @ Vw^T (168 outputs) ----
    if (tid < DYN_CH * DYN_K) {
        const float4* vr = (const float4*)(Vw + tid * HIDDEN);
        const float4* hh = (const float4*)h_sh;
        float acc = 0.f;
        #pragma unroll
        for (int j = 0; j < 32; ++j) {
            float4 v4 = vr[j]; float4 h4 = hh[j];
            acc = fmaf(v4.x, h4.x, acc); acc = fmaf(v4.y, h4.y, acc);
            acc = fmaf(v4.z, h4.z, acc); acc = fmaf(v4.w, h4.w, acc);
        }
        G_sh[tid] = acc;
    }
    __syncthreads();

    // ---- phase 3: Weff rows (KSCALE folded, Tb baked into k=21) ----
    for (int idx = tid; idx < HIDDEN * 24; idx += 1024) {
        int j = idx / 24, k = idx - j * 24;
        float val = 0.f;
        if (k < 21) {
            float acc = 0.f;
            #pragma unroll
            for (int c = 0; c < 8; ++c) {
                acc = fmaf(Uw[j * 8 + c], Fw[c * 21 + k], acc);
                acc = fmaf(Tw[j * 8 + c], G_sh[c * 21 + k], acc);
            }
            val = KSCALE * acc;
        } else if (k == 21) {
            val = KSCALE * Tb[j];
        }
        Weff_sh[idx] = val;
    }
    if (tid < HIDDEN) vv_sh[tid] = vw[tid];
    if (tid < 64) {
        float sv = vw[tid] + vw[tid + 64];
        #pragma unroll
        for (int o = 32; o > 0; o >>= 1) sv += __shfl_xor(sv, o);
        if (tid == 0) sumv_sh = sv;
    }
    __syncthreads();

    // ---- phase 4: A = Weff (j rows), B = sliding alpha window (t cols) ----
    // A lane: row j = n*16 + row, k = kb*8+e.  D lane: col t = row, rows j = n*16 + kb*4 + r.
    short8v wfrag[8];
    float4v vvr[8];
    #pragma unroll
    for (int n = 0; n < 8; ++n) {
        int j = n * 16 + row;
        short8v t = (short8v){0, 0, 0, 0, 0, 0, 0, 0};
        if (kb < 3) {
            const float* wb = &Weff_sh[j * 24 + kb * 8];
            setpk(t, 0, wb[0], wb[1]); setpk(t, 2, wb[2], wb[3]);
            setpk(t, 4, wb[4], wb[5]); setpk(t, 6, wb[6], wb[7]);
        }
        wfrag[n] = t;
        vvr[n] = *(const float4v*)&vv_sh[n * 16 + kb * 4];
    }

    for (int i = 0; i < 8; ++i) {
        const int t0 = (wid * 8 + i) * 16;
        // B[k][t] = a_sh[t0 + t + k];  k=21 -> 1.0 (Tb slot), k>=22 -> 0
        const float* ab = &a_sh[t0 + row + kb * 8];
        short8v af = (short8v){0, 0, 0, 0, 0, 0, 0, 0};
        if (kb < 3) {
            if (kb < 2) {
                setpk(af, 0, ab[0], ab[1]); setpk(af, 2, ab[2], ab[3]);
                setpk(af, 4, ab[4], ab[5]); setpk(af, 6, ab[6], ab[7]);
            } else {
                setpk(af, 0, ab[0], ab[1]); setpk(af, 2, ab[2], ab[3]);
                setpk(af, 4, ab[4], 1.0f);
            }
        }

        float4v accs[8];
        #pragma unroll
        for (int n = 0; n < 8; ++n) {
            float4v z = {0.f, 0.f, 0.f, 0.f};
            accs[n] = __builtin_amdgcn_mfma_f32_16x16x32_bf16(wfrag[n], af, z, 0, 0, 0);
        }

        // epilogue: ep = sum over this lane's 32 j's of v_j * sigma(p)
        float ep = 0.f;
        #pragma unroll
        for (int n = 0; n < 8; ++n) {
            #pragma unroll
            for (int r = 0; r < 4; ++r) {
                float sg = __builtin_amdgcn_rcpf(__builtin_amdgcn_exp2f(accs[n][r]) + 1.0f);
                ep = fmaf(vvr[n][r], sg, ep);
            }
        }
        ep += __shfl_xor(ep, 16);
        ep += __shfl_xor(ep, 32);
        if (lane < 16) e_sh[t0 + lane] = ep;
    }
    __syncthreads();

    // ---- final: prior + softmax, 2 positions per thread ----
    const float sumv = sumv_sh;
    const int tp = tid * 2;
    float tot0 = e_sh[tp], tot1 = e_sh[tp + 1];
    float pr0 = 0.f, pr1 = 0.f;
    #pragma unroll
    for (int k = 0; k < PRIOR_LEN; ++k) {
        pr0 = fmaf(a_sh[tp + k],     pf.v[k], pr0);
        pr1 = fmaf(a_sh[tp + 1 + k], pf.v[k], pr1);
    }
    float e0 = sumv - 2.f * tot0 + __logf(fmaxf(pr0, 1e-6f));
    float e1 = sumv - 2.f * tot1 + __logf(fmaxf(pr1, 1e-6f));

    const int lwid = tid >> 6, llane = tid & 63;
    float m = fmaxf(e0, e1);
    #pragma unroll
    for (int o = 32; o > 0; o >>= 1) m = fmaxf(m, __shfl_xor(m, o));
    if (llane == 0) red_max[lwid] = m;
    __syncthreads();
    float gm = red_max[0];
    #pragma unroll
    for (int w = 1; w < 16; ++w) gm = fmaxf(gm, red_max[w]);

    float x0 = __expf(e0 - gm), x1 = __expf(e1 - gm);
    float sloc = x0 + x1;
    #pragma unroll
    for (int o = 32; o > 0; o >>= 1) sloc += __shfl_xor(sloc, o);
    if (llane == 0) red_sum[lwid] = sloc;
    __syncthreads();
    float gs = 0.f;
    #pragma unroll
    for (int w = 0; w < 16; ++w) gs += red_sum[w];
    float inv = 1.0f / gs;

    ((float2*)(out + b * TT))[tid] = make_float2(x0 * inv, x1 * inv);
}

extern "C" void kernel_launch(void* const* d_in, const int* in_sizes, int n_in,
                              void* d_out, int out_size, void* d_ws, size_t ws_size,
                              hipStream_t stream) {
    (void)in_sizes; (void)n_in; (void)d_ws; (void)ws_size; (void)out_size;

    PriorArg pf;
    const double a = 0.1, bpr = 0.9;
    const int n = PRIOR_LEN - 1;
    const double norm = lgamma(a) + lgamma(bpr) - lgamma(a + bpr);
    for (int k = 0; k <= n; ++k) {
        double lp = lgamma((double)n + 1.0) - lgamma((double)k + 1.0)
                  - lgamma((double)(n - k) + 1.0)
                  + lgamma((double)k + a) + lgamma((double)(n - k) + bpr)
                  - lgamma((double)n + a + bpr) - norm;
        pf.v[PRIOR_LEN - 1 - k] = (float)exp(lp);
    }

    dca_kernel<<<dim3(BB), dim3(1024), 0, stream>>>(
        (const float*)d_in[0], (const float*)d_in[1], (const float*)d_in[2],
        (const float*)d_in[3], (const float*)d_in[4], (const float*)d_in[5],
        (const float*)d_in[6], (const float*)d_in[7], (const float*)d_in[8],
        (const float*)d_in[9], (float*)d_out, pf);
}

// Round 5
// 35.046 us; speedup vs baseline: 2.1205x; 1.2668x over previous
//
#include <hip/hip_runtime.h>
#include <hip/hip_bf16.h>
#include <cmath>

#define BB 256
#define TT 2048
#define ATTN_RNN 1024
#define HIDDEN 128
#define DYN_CH 8
#define DYN_K 21
#define PRIOR_LEN 11
#define KSCALE 2.8853900817779268f   /* 2*log2(e) */

typedef __attribute__((ext_vector_type(8))) short  short8v;   // 8 bf16
typedef __attribute__((ext_vector_type(4))) float  float4v;

struct PriorArg { float v[PRIOR_LEN]; };

__device__ __forceinline__ float fast_tanh(float x) {
    float e = __expf(2.0f * x);
    return 1.0f - 2.0f * __builtin_amdgcn_rcpf(e + 1.0f);
}

__device__ __forceinline__ void setpk(short8v& d, int i, float lo, float hi) {
    union { __hip_bfloat162 h; short s[2]; } u;
    u.h = __float22bfloat162_rn(make_float2(lo, hi));   // v_cvt_pk_bf16_f32
    d[i] = u.s[0]; d[i + 1] = u.s[1];
}

__global__ __launch_bounds__(1024, 4) void dca_kernel(
    const float* __restrict__ s,  const float* __restrict__ alpha,
    const float* __restrict__ Ww, const float* __restrict__ Wb,
    const float* __restrict__ Vw, const float* __restrict__ Fw,
    const float* __restrict__ Uw, const float* __restrict__ Tw,
    const float* __restrict__ Tb, const float* __restrict__ vw,
    float* __restrict__ out, PriorArg pf)
{
    const int b    = blockIdx.x;
    const int tid  = threadIdx.x;
    const int lane = tid & 63;
    const int wid  = tid >> 6;          // 0..15
    const int row  = lane & 15;         // A: j-row within tile / B: t-col within tile
    const int kb   = lane >> 4;         // 0..3 (k-block of 8)

    __shared__ __align__(16) float s_sh[ATTN_RNN];
    __shared__ float hpre_sh[HIDDEN];
    __shared__ __align__(16) float h_sh[HIDDEN];
    __shared__ float G_sh[DYN_CH * DYN_K];
    // Weff_sh[j][k] (stride 24): k0..20 = KSCALE*(U@F+T@G); k21 = KSCALE*Tb[j]; k22,23 = 0
    __shared__ __align__(16) float Weff_sh[HIDDEN * 24];
    __shared__ float vv_sh[HIDDEN];
    __shared__ __align__(16) float a_sh[TT + 48];         // a_sh[i] = alpha[b, i-10], 0-padded
    __shared__ __align__(16) float e_sh[TT];              // sum_j v_j * sigma  per position
    __shared__ float red_max[16], red_sum[16];
    __shared__ float sumv_sh;

    // ---- stage inputs ----
    for (int i = tid; i < ATTN_RNN; i += 1024) s_sh[i] = s[b * ATTN_RNN + i];
    for (int i = tid; i < TT + 48; i += 1024)
        a_sh[i] = (i >= 10 && i < TT + 10) ? alpha[b * TT + (i - 10)] : 0.0f;
    __syncthreads();

    // ---- phase 1 (coalesced): wave w owns rows j = w*8 .. w*8+7 ----
    // lane = (r = lane>>4: row-in-quad, l = lane&15: k-chunk of 64)
    // each f4 instr: 4 contiguous 256B runs (16 lines), vs 64 scattered lines before
    {
        const int r = lane >> 4;
        const int l = lane & 15;
        #pragma unroll
        for (int jg = 0; jg < 2; ++jg) {
            const int j = wid * 8 + jg * 4 + r;
            const float* wrow = Ww + j * ATTN_RNN + l * 4;
            float acc = 0.f;
            #pragma unroll
            for (int c = 0; c < 16; ++c) {
                float4 w  = *(const float4*)(wrow + c * 64);
                float4 sv = *(const float4*)(s_sh + c * 64 + l * 4);
                acc = fmaf(w.x, sv.x, acc); acc = fmaf(w.y, sv.y, acc);
                acc = fmaf(w.z, sv.z, acc); acc = fmaf(w.w, sv.w, acc);
            }
            acc += __shfl_xor(acc, 1);
            acc += __shfl_xor(acc, 2);
            acc += __shfl_xor(acc, 4);
            acc += __shfl_xor(acc, 8);
            if (l == 0) hpre_sh[j] = acc;
        }
    }
    __syncthreads();
    if (tid < HIDDEN) h_sh[tid] = fast_tanh(hpre_sh[tid] + Wb[tid]);
    __syncthreads();

    // ---- phase 2: G = h @ Vw^T (168 outputs) ----
    if (tid < DYN_CH * DYN_K) {
        const float4* vr = (const float4*)(Vw + tid * HIDDEN);
        const float4* hh = (const float4*)h_sh;
        float acc = 0.f;
        #pragma unroll
        for (int j = 0; j < 32; ++j) {
            float4 v4 = vr[j]; float4 h4 = hh[j];
            acc = fmaf(v4.x, h4.x, acc); acc = fmaf(v4.y, h4.y, acc);
            acc = fmaf(v4.z, h4.z, acc); acc = fmaf(v4.w, h4.w, acc);
        }
        G_sh[tid] = acc;
    }
    __syncthreads();

    // ---- phase 3: Weff rows (KSCALE folded, Tb baked into k=21) ----
    for (int idx = tid; idx < HIDDEN * 24; idx += 1024) {
        int j = idx / 24, k = idx - j * 24;
        float val = 0.f;
        if (k < 21) {
            float acc = 0.f;
            #pragma unroll
            for (int c = 0; c < 8; ++c) {
                acc = fmaf(Uw[j * 8 + c], Fw[c * 21 + k], acc);
                acc = fmaf(Tw[j * 8 + c], G_sh[c * 21 + k], acc);
            }
            val = KSCALE * acc;
        } else if (k == 21) {
            val = KSCALE * Tb[j];
        }
        Weff_sh[idx] = val;
    }
    if (tid < HIDDEN) vv_sh[tid] = vw[tid];
    if (tid < 64) {
        float sv = vw[tid] + vw[tid + 64];
        #pragma unroll
        for (int o = 32; o > 0; o >>= 1) sv += __shfl_xor(sv, o);
        if (tid == 0) sumv_sh = sv;
    }
    __syncthreads();

    // ---- phase 4: A = Weff (j rows), B = sliding alpha window (t cols) ----
    // A lane: row j = n*16 + row, k = kb*8+e.  D lane: col t = row, rows j = n*16 + kb*4 + r.
    short8v wfrag[8];
    float4v vvr[8];
    #pragma unroll
    for (int n = 0; n < 8; ++n) {
        int j = n * 16 + row;
        short8v t = (short8v){0, 0, 0, 0, 0, 0, 0, 0};
        if (kb < 3) {
            const float* wb = &Weff_sh[j * 24 + kb * 8];
            setpk(t, 0, wb[0], wb[1]); setpk(t, 2, wb[2], wb[3]);
            setpk(t, 4, wb[4], wb[5]); setpk(t, 6, wb[6], wb[7]);
        }
        wfrag[n] = t;
        vvr[n] = *(const float4v*)&vv_sh[n * 16 + kb * 4];
    }

    for (int i = 0; i < 8; ++i) {
        const int t0 = (wid * 8 + i) * 16;
        // B[k][t] = a_sh[t0 + t + k];  k=21 -> 1.0 (Tb slot), k>=22 -> 0
        const float* ab = &a_sh[t0 + row + kb * 8];
        short8v af = (short8v){0, 0, 0, 0, 0, 0, 0, 0};
        if (kb < 3) {
            if (kb < 2) {
                setpk(af, 0, ab[0], ab[1]); setpk(af, 2, ab[2], ab[3]);
                setpk(af, 4, ab[4], ab[5]); setpk(af, 6, ab[6], ab[7]);
            } else {
                setpk(af, 0, ab[0], ab[1]); setpk(af, 2, ab[2], ab[3]);
                setpk(af, 4, ab[4], 1.0f);
            }
        }

        float4v accs[8];
        #pragma unroll
        for (int n = 0; n < 8; ++n) {
            float4v z = {0.f, 0.f, 0.f, 0.f};
            accs[n] = __builtin_amdgcn_mfma_f32_16x16x32_bf16(wfrag[n], af, z, 0, 0, 0);
        }

        // epilogue: ep = sum over this lane's 32 j's of v_j * sigma(p)
        float ep = 0.f;
        #pragma unroll
        for (int n = 0; n < 8; ++n) {
            #pragma unroll
            for (int r = 0; r < 4; ++r) {
                float sg = __builtin_amdgcn_rcpf(__builtin_amdgcn_exp2f(accs[n][r]) + 1.0f);
                ep = fmaf(vvr[n][r], sg, ep);
            }
        }
        ep += __shfl_xor(ep, 16);
        ep += __shfl_xor(ep, 32);
        if (lane < 16) e_sh[t0 + lane] = ep;
    }
    __syncthreads();

    // ---- final: prior + softmax, 2 positions per thread ----
    const float sumv = sumv_sh;
    const int tp = tid * 2;
    float tot0 = e_sh[tp], tot1 = e_sh[tp + 1];
    float pr0 = 0.f, pr1 = 0.f;
    #pragma unroll
    for (int k = 0; k < PRIOR_LEN; ++k) {
        pr0 = fmaf(a_sh[tp + k],     pf.v[k], pr0);
        pr1 = fmaf(a_sh[tp + 1 + k], pf.v[k], pr1);
    }
    float e0 = sumv - 2.f * tot0 + __logf(fmaxf(pr0, 1e-6f));
    float e1 = sumv - 2.f * tot1 + __logf(fmaxf(pr1, 1e-6f));

    const int lwid = tid >> 6, llane = tid & 63;
    float m = fmaxf(e0, e1);
    #pragma unroll
    for (int o = 32; o > 0; o >>= 1) m = fmaxf(m, __shfl_xor(m, o));
    if (llane == 0) red_max[lwid] = m;
    __syncthreads();
    float gm = red_max[0];
    #pragma unroll
    for (int w = 1; w < 16; ++w) gm = fmaxf(gm, red_max[w]);

    float x0 = __expf(e0 - gm), x1 = __expf(e1 - gm);
    float sloc = x0 + x1;
    #pragma unroll
    for (int o = 32; o > 0; o >>= 1) sloc += __shfl_xor(sloc, o);
    if (llane == 0) red_sum[lwid] = sloc;
    __syncthreads();
    float gs = 0.f;
    #pragma unroll
    for (int w = 0; w < 16; ++w) gs += red_sum[w];
    float inv = 1.0f / gs;

    ((float2*)(out + b * TT))[tid] = make_float2(x0 * inv, x1 * inv);
}

extern "C" void kernel_launch(void* const* d_in, const int* in_sizes, int n_in,
                              void* d_out, int out_size, void* d_ws, size_t ws_size,
                              hipStream_t stream) {
    (void)in_sizes; (void)n_in; (void)d_ws; (void)ws_size; (void)out_size;

    PriorArg pf;
    const double a = 0.1, bpr = 0.9;
    const int n = PRIOR_LEN - 1;
    const double norm = lgamma(a) + lgamma(bpr) - lgamma(a + bpr);
    for (int k = 0; k <= n; ++k) {
        double lp = lgamma((double)n + 1.0) - lgamma((double)k + 1.0)
                  - lgamma((double)(n - k) + 1.0)
                  + lgamma((double)k + a) + lgamma((double)(n - k) + bpr)
                  - lgamma((double)n + a + bpr) - norm;
        pf.v[PRIOR_LEN - 1 - k] = (float)exp(lp);
    }

    dca_kernel<<<dim3(BB), dim3(1024), 0, stream>>>(
        (const float*)d_in[0], (const float*)d_in[1], (const float*)d_in[2],
        (const float*)d_in[3], (const float*)d_in[4], (const float*)d_in[5],
        (const float*)d_in[6], (const float*)d_in[7], (const float*)d_in[8],
        (const float*)d_in[9], (float*)d_out, pf);
}

// Round 6
// 33.266 us; speedup vs baseline: 2.2339x; 1.0535x over previous
//
#include <hip/hip_runtime.h>
#include <hip/hip_bf16.h>
#include <cmath>

#define BB 256
#define TT 2048
#define ATTN_RNN 1024
#define HIDDEN 128
#define DYN_CH 8
#define DYN_K 21
#define PRIOR_LEN 11
#define KSCALE 2.8853900817779268f   /* 2*log2(e) */

typedef __attribute__((ext_vector_type(8))) short  short8v;   // 8 bf16
typedef __attribute__((ext_vector_type(4))) float  float4v;

struct PriorArg { float v[PRIOR_LEN]; };

__device__ __forceinline__ float fast_tanh(float x) {
    float e = __expf(2.0f * x);
    return 1.0f - 2.0f * __builtin_amdgcn_rcpf(e + 1.0f);
}

__device__ __forceinline__ unsigned pk_bf16(float lo, float hi) {
    union { __hip_bfloat162 h; unsigned u; } u;
    u.h = __float22bfloat162_rn(make_float2(lo, hi));   // v_cvt_pk_bf16_f32
    return u.u;
}

__device__ __forceinline__ void setpk(short8v& d, int i, float lo, float hi) {
    union { __hip_bfloat162 h; short s[2]; } u;
    u.h = __float22bfloat162_rn(make_float2(lo, hi));
    d[i] = u.s[0]; d[i + 1] = u.s[1];
}

__global__ __launch_bounds__(1024, 4) void dca_kernel(
    const float* __restrict__ s,  const float* __restrict__ alpha,
    const float* __restrict__ Ww, const float* __restrict__ Wb,
    const float* __restrict__ Vw, const float* __restrict__ Fw,
    const float* __restrict__ Uw, const float* __restrict__ Tw,
    const float* __restrict__ Tb, const float* __restrict__ vw,
    float* __restrict__ out, PriorArg pf)
{
    const int b    = blockIdx.x;
    const int tid  = threadIdx.x;
    const int lane = tid & 63;
    const int wid  = tid >> 6;          // 0..15
    const int row  = lane & 15;
    const int kb   = lane >> 4;         // 0..3 (k-block of 8)

    __shared__ __align__(16) float s_sh[ATTN_RNN];
    __shared__ __align__(16) float h_sh[HIDDEN];
    __shared__ float G_sh[DYN_CH * DYN_K];
    // Wpk[j][kp]: bf16 pair (k=2kp, 2kp+1), KSCALE folded; kp=10 hi = KSCALE*Tb; kp=11 = 0
    __shared__ __align__(16) unsigned Wpk[HIDDEN * 12];
    __shared__ float vv_sh[HIDDEN];
    __shared__ __align__(16) float a_sh[TT + 48];   // a_sh[i] = alpha[b, i-10], 0-padded
    __shared__ __align__(16) float e_sh[TT];
    __shared__ float red_max[16], red_sum[16];
    __shared__ float sumv_sh;

    // ---- stage inputs (+ vv, sumv — all independent work before 1st barrier) ----
    s_sh[tid & (ATTN_RNN - 1)] = s[b * ATTN_RNN + (tid & (ATTN_RNN - 1))];
    for (int i = tid; i < TT + 48; i += 1024)
        a_sh[i] = (i >= 10 && i < TT + 10) ? alpha[b * TT + (i - 10)] : 0.0f;
    if (tid < HIDDEN) vv_sh[tid] = vw[tid];
    if (tid < 64) {
        float sv = vw[tid] + vw[tid + 64];
        #pragma unroll
        for (int o = 32; o > 0; o >>= 1) sv += __shfl_xor(sv, o);
        if (tid == 0) sumv_sh = sv;
    }
    __syncthreads();

    // ---- phase 1 (coalesced) + fused tanh: wave w owns j = w*8..w*8+7 ----
    {
        const int r = lane >> 4;
        const int l = lane & 15;
        #pragma unroll
        for (int jg = 0; jg < 2; ++jg) {
            const int j = wid * 8 + jg * 4 + r;
            const float* wrow = Ww + j * ATTN_RNN + l * 4;
            float acc = 0.f;
            #pragma unroll
            for (int c = 0; c < 16; ++c) {
                float4 w  = *(const float4*)(wrow + c * 64);
                float4 sv = *(const float4*)(s_sh + c * 64 + l * 4);
                acc = fmaf(w.x, sv.x, acc); acc = fmaf(w.y, sv.y, acc);
                acc = fmaf(w.z, sv.z, acc); acc = fmaf(w.w, sv.w, acc);
            }
            acc += __shfl_xor(acc, 1);
            acc += __shfl_xor(acc, 2);
            acc += __shfl_xor(acc, 4);
            acc += __shfl_xor(acc, 8);
            if (l == 0) h_sh[j] = fast_tanh(acc + Wb[j]);
        }
    }
    __syncthreads();

    // ---- phase 2: G = h @ Vw^T, 4-way split-K over 672 threads ----
    if (tid < DYN_CH * DYN_K * 4) {
        const int g = tid >> 2, part = tid & 3;
        const float4* vr = (const float4*)(Vw + g * HIDDEN + part * 32);
        const float4* hh = (const float4*)(h_sh + part * 32);
        float acc = 0.f;
        #pragma unroll
        for (int c = 0; c < 8; ++c) {
            float4 v4 = vr[c]; float4 h4 = hh[c];
            acc = fmaf(v4.x, h4.x, acc); acc = fmaf(v4.y, h4.y, acc);
            acc = fmaf(v4.z, h4.z, acc); acc = fmaf(v4.w, h4.w, acc);
        }
        acc += __shfl_xor(acc, 1);
        acc += __shfl_xor(acc, 2);
        if (part == 0) G_sh[g] = acc;
    }
    __syncthreads();

    // ---- phase 3: bf16-pair-packed Weff (KSCALE folded, Tb in k=21 slot) ----
    for (int idx = tid; idx < HIDDEN * 12; idx += 1024) {
        const int j = idx / 12, kp = idx - j * 12;
        float v0 = 0.f, v1 = 0.f;
        if (kp < 11) {
            const int k0 = 2 * kp;
            float a0 = 0.f, a1 = 0.f;
            #pragma unroll
            for (int c = 0; c < 8; ++c) {
                const float u = Uw[j * 8 + c], t = Tw[j * 8 + c];
                a0 = fmaf(u, Fw[c * 21 + k0], a0);
                a0 = fmaf(t, G_sh[c * 21 + k0], a0);
                if (kp < 10) {
                    a1 = fmaf(u, Fw[c * 21 + k0 + 1], a1);
                    a1 = fmaf(t, G_sh[c * 21 + k0 + 1], a1);
                }
            }
            v0 = KSCALE * a0;
            v1 = (kp < 10) ? KSCALE * a1 : KSCALE * Tb[j];
        }
        Wpk[idx] = pk_bf16(v0, v1);
    }
    __syncthreads();

    // ---- phase 4: A = Weff (j rows), B = sliding alpha window (t cols) ----
    short8v wfrag[8];
    float4v vvr[8];
    #pragma unroll
    for (int n = 0; n < 8; ++n) {
        const int j = n * 16 + row;
        wfrag[n] = (kb < 3) ? *(const short8v*)&Wpk[j * 12 + kb * 4]
                            : (short8v){0, 0, 0, 0, 0, 0, 0, 0};
        vvr[n] = *(const float4v*)&vv_sh[n * 16 + kb * 4];
    }

    for (int i = 0; i < 8; ++i) {
        const int t0 = (wid * 8 + i) * 16;
        const float* ab = &a_sh[t0 + row + kb * 8];
        short8v af = (short8v){0, 0, 0, 0, 0, 0, 0, 0};
        if (kb < 3) {
            if (kb < 2) {
                setpk(af, 0, ab[0], ab[1]); setpk(af, 2, ab[2], ab[3]);
                setpk(af, 4, ab[4], ab[5]); setpk(af, 6, ab[6], ab[7]);
            } else {
                setpk(af, 0, ab[0], ab[1]); setpk(af, 2, ab[2], ab[3]);
                setpk(af, 4, ab[4], 1.0f);          // k=21 -> Tb slot
            }
        }

        float4v accs[8];
        #pragma unroll
        for (int n = 0; n < 8; ++n) {
            float4v z = {0.f, 0.f, 0.f, 0.f};
            accs[n] = __builtin_amdgcn_mfma_f32_16x16x32_bf16(wfrag[n], af, z, 0, 0, 0);
        }

        float ep = 0.f;
        #pragma unroll
        for (int n = 0; n < 8; ++n) {
            #pragma unroll
            for (int r = 0; r < 4; ++r) {
                float sg = __builtin_amdgcn_rcpf(__builtin_amdgcn_exp2f(accs[n][r]) + 1.0f);
                ep = fmaf(vvr[n][r], sg, ep);
            }
        }
        ep += __shfl_xor(ep, 16);
        ep += __shfl_xor(ep, 32);
        if (lane < 16) e_sh[t0 + lane] = ep;
    }
    __syncthreads();

    // ---- final: prior + softmax, 2 positions per thread ----
    const float sumv = sumv_sh;
    const int tp = tid * 2;
    float tot0 = e_sh[tp], tot1 = e_sh[tp + 1];
    float pr0 = 0.f, pr1 = 0.f;
    #pragma unroll
    for (int k = 0; k < PRIOR_LEN; ++k) {
        pr0 = fmaf(a_sh[tp + k],     pf.v[k], pr0);
        pr1 = fmaf(a_sh[tp + 1 + k], pf.v[k], pr1);
    }
    float e0 = sumv - 2.f * tot0 + __logf(fmaxf(pr0, 1e-6f));
    float e1 = sumv - 2.f * tot1 + __logf(fmaxf(pr1, 1e-6f));

    float m = fmaxf(e0, e1);
    #pragma unroll
    for (int o = 32; o > 0; o >>= 1) m = fmaxf(m, __shfl_xor(m, o));
    if (lane == 0) red_max[wid] = m;
    __syncthreads();
    float gm = red_max[0];
    #pragma unroll
    for (int w = 1; w < 16; ++w) gm = fmaxf(gm, red_max[w]);

    float x0 = __expf(e0 - gm), x1 = __expf(e1 - gm);
    float sloc = x0 + x1;
    #pragma unroll
    for (int o = 32; o > 0; o >>= 1) sloc += __shfl_xor(sloc, o);
    if (lane == 0) red_sum[wid] = sloc;
    __syncthreads();
    float gs = 0.f;
    #pragma unroll
    for (int w = 0; w < 16; ++w) gs += red_sum[w];
    float inv = 1.0f / gs;

    ((float2*)(out + b * TT))[tid] = make_float2(x0 * inv, x1 * inv);
}

extern "C" void kernel_launch(void* const* d_in, const int* in_sizes, int n_in,
                              void* d_out, int out_size, void* d_ws, size_t ws_size,
                              hipStream_t stream) {
    (void)in_sizes; (void)n_in; (void)d_ws; (void)ws_size; (void)out_size;

    PriorArg pf;
    const double a = 0.1, bpr = 0.9;
    const int n = PRIOR_LEN - 1;
    const double norm = lgamma(a) + lgamma(bpr) - lgamma(a + bpr);
    for (int k = 0; k <= n; ++k) {
        double lp = lgamma((double)n + 1.0) - lgamma((double)k + 1.0)
                  - lgamma((double)(n - k) + 1.0)
                  + lgamma((double)k + a) + lgamma((double)(n - k) + bpr)
                  - lgamma((double)n + a + bpr) - norm;
        pf.v[PRIOR_LEN - 1 - k] = (float)exp(lp);
    }

    dca_kernel<<<dim3(BB), dim3(1024), 0, stream>>>(
        (const float*)d_in[0], (const float*)d_in[1], (const float*)d_in[2],
        (const float*)d_in[3], (const float*)d_in[4], (const float*)d_in[5],
        (const float*)d_in[6], (const float*)d_in[7], (const float*)d_in[8],
        (const float*)d_in[9], (float*)d_out, pf);
}